// Round 5
// baseline (756.606 us; speedup 1.0000x reference)
//
#include <hip/hip_runtime.h>

// Problem constants
#define NN 50000      // nodes
#define NE 800000     // edges
#define MP 50048      // padded rows = 782*64
#define GG 64         // graphs
#define HD 512        // hidden/feature dim
#define K2 1024       // fused K (agg | self)
#define SCAN_BLKS 196 // ceil(50000/256)

typedef __attribute__((ext_vector_type(8))) short bf16x8;
typedef __attribute__((ext_vector_type(4))) float f32x4;

__device__ __forceinline__ unsigned short f2bf(float f) {
  unsigned u = __builtin_bit_cast(unsigned, f);
  u += 0x7fffu + ((u >> 16) & 1u);
  return (unsigned short)(u >> 16);
}
__device__ __forceinline__ float bf2f(unsigned short h) {
  unsigned u = ((unsigned)h) << 16;
  return __builtin_bit_cast(float, u);
}

__device__ __forceinline__ void g2l16(const void* g, void* l) {
  __builtin_amdgcn_global_load_lds(
      (const __attribute__((address_space(1))) unsigned int*)g,
      (__attribute__((address_space(3))) unsigned int*)l, 16, 0, 0);
}

// ---------------- fused prologue: weight transpose x2 + x->bf16 pad + degree histogram
// blocks [0,256): Wt transpose tiles; [256,2304): cvtpad x; [2304,2816): hist
__global__ __launch_bounds__(256) void prep_kernel(
    const float* __restrict__ x, unsigned short* __restrict__ xb,
    const float* __restrict__ Wr0, const float* __restrict__ Ws0, unsigned short* __restrict__ Wt0,
    const float* __restrict__ Wr1, const float* __restrict__ Ws1, unsigned short* __restrict__ Wt1,
    const int* __restrict__ ei, int* __restrict__ deg) {
  int b = blockIdx.x, t = threadIdx.x;
  if (b < 256) {
    // 64x64 transpose tile: W[k][n] (fp32) -> Wt[n][half*512+k] (bf16)
    __shared__ float sh[64][65];
    int layer = b >> 7, tl = b & 127;
    int tn = tl >> 4, tk = tl & 15;
    int half = tk >> 3;
    int kw = (tk & 7) * 64, n0 = tn * 64;
    const float* W = layer ? (half ? Ws1 : Wr1) : (half ? Ws0 : Wr0);
    unsigned short* Wt = layer ? Wt1 : Wt0;
    int nn = t & 63;
    int kb = t >> 6;
#pragma unroll
    for (int i = 0; i < 16; i++) {
      int kk = kb + i * 4;
      sh[kk][nn] = W[(size_t)(kw + kk) * HD + n0 + nn];
    }
    __syncthreads();
    int kk2 = t & 63;
#pragma unroll
    for (int i = 0; i < 16; i++) {
      int nn2 = kb + i * 4;
      Wt[(size_t)(n0 + nn2) * K2 + half * HD + kw + kk2] = f2bf(sh[kk2][nn2]);
    }
  } else if (b < 2304) {
    const long long total4 = (long long)MP * HD / 4;
    for (long long i = (long long)(b - 256) * 256 + t; i < total4; i += 2048LL * 256) {
      int r = (int)((i * 4) >> 9);
      float4 v = make_float4(0.f, 0.f, 0.f, 0.f);
      if (r < NN) v = ((const float4*)x)[i];
      ushort4 o;
      o.x = f2bf(v.x); o.y = f2bf(v.y); o.z = f2bf(v.z); o.w = f2bf(v.w);
      ((ushort4*)xb)[i] = o;
    }
  } else {
    for (int i = (b - 2304) * 256 + t; i < NE; i += 512 * 256) {
      atomicAdd(&deg[ei[NE + i]], 1);
    }
  }
}

// ---------------- CSR scan (3-phase) + fill
__global__ __launch_bounds__(256) void scan1_kernel(const int* __restrict__ deg,
                                                    int* __restrict__ tmp,
                                                    int* __restrict__ bsum) {
  __shared__ int sh[256];
  int t = threadIdx.x;
  int i = blockIdx.x * 256 + t;
  int v = (i < NN) ? deg[i] : 0;
  sh[t] = v;
  __syncthreads();
#pragma unroll
  for (int off = 1; off < 256; off <<= 1) {
    int u = (t >= off) ? sh[t - off] : 0;
    __syncthreads();
    sh[t] += u;
    __syncthreads();
  }
  if (i < NN) tmp[i] = sh[t] - v;
  if (t == 255) bsum[blockIdx.x] = sh[255];
}

__global__ __launch_bounds__(256) void scan2_kernel(int* __restrict__ bsum,
                                                    int* __restrict__ row_ptr) {
  __shared__ int sh[256];
  int t = threadIdx.x;
  int v = (t < SCAN_BLKS) ? bsum[t] : 0;
  sh[t] = v;
  __syncthreads();
#pragma unroll
  for (int off = 1; off < 256; off <<= 1) {
    int u = (t >= off) ? sh[t - off] : 0;
    __syncthreads();
    sh[t] += u;
    __syncthreads();
  }
  if (t < SCAN_BLKS) bsum[t] = sh[t] - v;
  if (t == 255) row_ptr[NN] = sh[255];
}

__global__ __launch_bounds__(256) void scan3_kernel(const int* __restrict__ tmp,
                                                    const int* __restrict__ bsum,
                                                    int* __restrict__ row_ptr,
                                                    int* __restrict__ cursor) {
  int i = blockIdx.x * 256 + threadIdx.x;
  if (i < NN) {
    int r = tmp[i] + bsum[blockIdx.x];
    row_ptr[i] = r;
    cursor[i] = r;
  }
}

__global__ void fill_kernel(const int* __restrict__ ei, int* __restrict__ cursor,
                            int* __restrict__ col) {
  int i = blockIdx.x * 256 + threadIdx.x;
  if (i < NE) {
    int d = ei[NE + i];
    int p = atomicAdd(&cursor[d], 1);
    col[p] = ei[i];
  }
}

// ---------------- gather aggregation: 2 rows per wave for 2x memory-level parallelism
#define ACC8(v, a)                                        \
  a[0] += bf2f((unsigned short)((v).x & 0xffff));         \
  a[1] += bf2f((unsigned short)((v).x >> 16));            \
  a[2] += bf2f((unsigned short)((v).y & 0xffff));         \
  a[3] += bf2f((unsigned short)((v).y >> 16));            \
  a[4] += bf2f((unsigned short)((v).z & 0xffff));         \
  a[5] += bf2f((unsigned short)((v).z >> 16));            \
  a[6] += bf2f((unsigned short)((v).w & 0xffff));         \
  a[7] += bf2f((unsigned short)((v).w >> 16));

__global__ __launch_bounds__(256) void gather_kernel(const unsigned short* __restrict__ X,
                                                     const int* __restrict__ row_ptr,
                                                     const int* __restrict__ col,
                                                     unsigned short* __restrict__ out) {
  int wid = (blockIdx.x * 256 + threadIdx.x) >> 6;
  int lane = threadIdx.x & 63;
  int rowA = wid * 2, rowB = wid * 2 + 1;
  if (rowA >= MP) return;
  float aA[8] = {0.f, 0.f, 0.f, 0.f, 0.f, 0.f, 0.f, 0.f};
  float aB[8] = {0.f, 0.f, 0.f, 0.f, 0.f, 0.f, 0.f, 0.f};
  int r0a = 0, r1a = 0, r0b = 0, r1b = 0;
  if (rowA < NN) { r0a = row_ptr[rowA]; r1a = row_ptr[rowA + 1]; }
  if (rowB < NN) { r0b = row_ptr[rowB]; r1b = row_ptr[rowB + 1]; }
  int baseA = r0a, baseB = r0b;
  while (baseA < r1a || baseB < r1b) {
    int cntA = r1a - baseA; cntA = cntA < 0 ? 0 : (cntA > 64 ? 64 : cntA);
    int cntB = r1b - baseB; cntB = cntB < 0 ? 0 : (cntB > 64 ? 64 : cntB);
    int mycA = (lane < cntA) ? col[baseA + lane] : 0;
    int mycB = (lane < cntB) ? col[baseB + lane] : 0;
    int n = cntA > cntB ? cntA : cntB;
#pragma unroll 4
    for (int j = 0; j < n; j++) {
      if (j < cntA) {
        int c = __shfl(mycA, j);
        uint4 v = *(const uint4*)(X + (size_t)c * HD + lane * 8);
        ACC8(v, aA)
      }
      if (j < cntB) {
        int c = __shfl(mycB, j);
        uint4 v = *(const uint4*)(X + (size_t)c * HD + lane * 8);
        ACC8(v, aB)
      }
    }
    baseA += 64; baseB += 64;
  }
  uint4 oA, oB;
  oA.x = ((unsigned)f2bf(aA[1]) << 16) | f2bf(aA[0]);
  oA.y = ((unsigned)f2bf(aA[3]) << 16) | f2bf(aA[2]);
  oA.z = ((unsigned)f2bf(aA[5]) << 16) | f2bf(aA[4]);
  oA.w = ((unsigned)f2bf(aA[7]) << 16) | f2bf(aA[6]);
  oB.x = ((unsigned)f2bf(aB[1]) << 16) | f2bf(aB[0]);
  oB.y = ((unsigned)f2bf(aB[3]) << 16) | f2bf(aB[2]);
  oB.z = ((unsigned)f2bf(aB[5]) << 16) | f2bf(aB[4]);
  oB.w = ((unsigned)f2bf(aB[7]) << 16) | f2bf(aB[6]);
  *(uint4*)(out + (size_t)rowA * HD + lane * 8) = oA;
  *(uint4*)(out + (size_t)rowB * HD + lane * 8) = oB;
}

// ---------------- fused GEMM v3: BM=64, BN=512 (full N), BK=64, dbuf prefetch 2-phase
// A fetched once; B (2 MB) stays L2-resident per XCD. 8 waves, each 64x64 output.
__global__ __launch_bounds__(512, 2) void gemm_kernel(
    const unsigned short* __restrict__ A0, const unsigned short* __restrict__ A1,
    const unsigned short* __restrict__ Wt, const float* __restrict__ bias,
    unsigned short* __restrict__ Hout) {
  __shared__ __align__(16) unsigned short Ads[2][64 * 64];
  __shared__ __align__(16) unsigned short Bds[2][512 * 64];

  const int tid = threadIdx.x;
  const int lane = tid & 63;
  const int wv = tid >> 6;   // 0..7 -> 64-col slice

  // bijective XCD-chunk swizzle over 782 blocks (m204)
  const int nwg = 782;
  const int orig = blockIdx.x;
  const int q = nwg >> 3, r8 = nwg & 7;
  const int xcd = orig & 7;
  const int mt = (xcd < r8 ? xcd * (q + 1) : r8 * (q + 1) + (xcd - r8) * q) + (orig >> 3);
  const int row0 = mt * 64;

  f32x4 acc[4][4];
#pragma unroll
  for (int i = 0; i < 4; i++)
#pragma unroll
    for (int j = 0; j < 4; j++) acc[i][j] = (f32x4)(0.f);

  const int sr = tid >> 3;         // 0..63: staging row within 64-row group
  const int sc = tid & 7;          // 16B chunk within 128B row
  const int csw = sc ^ (sr & 7);   // pre-swizzled source chunk (T2 / m201 pattern)

  int cur = 0;
  // prologue stage kt=0
  {
    g2l16(A0 + (size_t)(row0 + sr) * HD + csw * 8, &Ads[0][tid * 8]);
#pragma unroll
    for (int it = 0; it < 8; it++)
      g2l16(Wt + (size_t)(it * 64 + sr) * K2 + csw * 8, &Bds[0][it * 4096 + tid * 8]);
  }
  __syncthreads();

  for (int kt = 0; kt < 16; ++kt) {
    if (kt < 15) {  // prefetch next K-tile into the other buffer
      const int k0 = (kt + 1) * 64;
      const unsigned short* Asrc = (k0 < HD) ? A0 : A1;
      const int ka = k0 & (HD - 1);
      g2l16(Asrc + (size_t)(row0 + sr) * HD + ka + csw * 8, &Ads[cur ^ 1][tid * 8]);
#pragma unroll
      for (int it = 0; it < 8; it++)
        g2l16(Wt + (size_t)(it * 64 + sr) * K2 + k0 + csw * 8, &Bds[cur ^ 1][it * 4096 + tid * 8]);
    }
#pragma unroll
    for (int kk = 0; kk < 2; ++kk) {
      bf16x8 af[4], bfr[4];
#pragma unroll
      for (int m = 0; m < 4; m++) {
        int r = m * 16 + (lane & 15);
        int ck = (kk * 4 + (lane >> 4)) ^ (r & 7);
        af[m] = *(const bf16x8*)&Ads[cur][r * 64 + ck * 8];
      }
#pragma unroll
      for (int n = 0; n < 4; n++) {
        int r = wv * 64 + n * 16 + (lane & 15);
        int ck = (kk * 4 + (lane >> 4)) ^ (r & 7);
        bfr[n] = *(const bf16x8*)&Bds[cur][r * 64 + ck * 8];
      }
#pragma unroll
      for (int m = 0; m < 4; m++)
#pragma unroll
        for (int n = 0; n < 4; n++)
          acc[m][n] = __builtin_amdgcn_mfma_f32_16x16x32_bf16(af[m], bfr[n], acc[m][n], 0, 0, 0);
    }
    __syncthreads();   // drains this wave's DMA (vmcnt0) + all waves done reading cur
    cur ^= 1;
  }

#pragma unroll
  for (int n = 0; n < 4; n++) {
    int c = wv * 64 + n * 16 + (lane & 15);
    float bv = bias[c];
#pragma unroll
    for (int m = 0; m < 4; m++) {
      int rbase = row0 + m * 16 + (lane >> 4) * 4;
#pragma unroll
      for (int r = 0; r < 4; r++) {
        float v = acc[m][n][r] + bv;
        v = v > 0.f ? v : 0.f;
        Hout[(size_t)(rbase + r) * HD + c] = f2bf(v);
      }
    }
  }
}

// ---------------- mean-pool partial sums (batch is sorted; binary search boundaries)
__device__ __forceinline__ int lbound(const int* b, int v) {
  int lo = 0, hi = NN;
  while (lo < hi) { int m = (lo + hi) >> 1; if (b[m] < v) lo = m + 1; else hi = m; }
  return lo;
}

__global__ void pool_kernel(const unsigned short* __restrict__ H, const int* __restrict__ batch,
                            float* __restrict__ pooled) {
  int b = blockIdx.x;          // 64 graphs * 2 col-halves * 8 row-chunks
  int g = b >> 4;
  int half = (b >> 3) & 1;
  int chunk = b & 7;
  int col = half * 256 + threadIdx.x;
  int start = lbound(batch, g);
  int end = lbound(batch, g + 1);
  int len = end - start;
  int r0 = start + (int)(((long long)len * chunk) >> 3);
  int r1 = start + (int)(((long long)len * (chunk + 1)) >> 3);
  float s = 0.f;
  for (int r = r0; r < r1; r++) s += bf2f(H[(size_t)r * HD + col]);
  atomicAdd(&pooled[g * HD + col], s);
}

// ---------------- classifier: out[g][c] = relu(pooled/cnt) @ Wl + bl
__global__ void final_kernel(const float* __restrict__ pooled, const int* __restrict__ batch,
                             const float* __restrict__ Wl, const float* __restrict__ bl,
                             float* __restrict__ out) {
  int g = blockIdx.x;
  int t = threadIdx.x;   // 256
  int lane = t & 63, wv = t >> 6;
  int start = lbound(batch, g);
  int end = lbound(batch, g + 1);
  float cnt = (float)(end - start);
  if (cnt < 1.f) cnt = 1.f;
  float a[10];
#pragma unroll
  for (int c = 0; c < 10; c++) a[c] = 0.f;
  for (int n = t; n < HD; n += 256) {
    float p = pooled[g * HD + n] / cnt;
    p = p > 0.f ? p : 0.f;
#pragma unroll
    for (int c = 0; c < 10; c++) a[c] += p * Wl[n * 10 + c];
  }
  __shared__ float red[10][4];
#pragma unroll
  for (int c = 0; c < 10; c++) {
    float v = a[c];
#pragma unroll
    for (int off = 32; off >= 1; off >>= 1) v += __shfl_down(v, off);
    if (lane == 0) red[c][wv] = v;
  }
  __syncthreads();
  if (t < 10) out[g * 10 + t] = red[t][0] + red[t][1] + red[t][2] + red[t][3] + bl[t];
}

extern "C" void kernel_launch(void* const* d_in, const int* in_sizes, int n_in,
                              void* d_out, int out_size, void* d_ws, size_t ws_size,
                              hipStream_t stream) {
  const float* x   = (const float*)d_in[0];
  const int* ei    = (const int*)d_in[1];
  const int* batch = (const int*)d_in[2];
  const float* Wr0 = (const float*)d_in[3];
  const float* br0 = (const float*)d_in[4];
  const float* Ws0 = (const float*)d_in[5];
  const float* Wr1 = (const float*)d_in[6];
  const float* br1 = (const float*)d_in[7];
  const float* Ws1 = (const float*)d_in[8];
  const float* Wl  = (const float*)d_in[9];
  const float* bl  = (const float*)d_in[10];
  float* out = (float*)d_out;

  char* ws = (char*)d_ws;
  size_t off = 0;
  auto alloc = [&](size_t bytes) { char* p = ws + off; off += (bytes + 255) & ~255ULL; return p; };
  unsigned short* xb   = (unsigned short*)alloc((size_t)MP * HD * 2);
  unsigned short* h0   = (unsigned short*)alloc((size_t)MP * HD * 2);
  unsigned short* aggb = (unsigned short*)alloc((size_t)MP * HD * 2);
  unsigned short* Wt0  = (unsigned short*)alloc((size_t)HD * K2 * 2);
  unsigned short* Wt1  = (unsigned short*)alloc((size_t)HD * K2 * 2);
  float* pooled        = (float*)alloc((size_t)GG * HD * 4);
  int* deg             = (int*)alloc((size_t)NN * 4);
  int* row_ptr         = (int*)alloc((size_t)(NN + 1) * 4);
  int* cursor          = (int*)alloc((size_t)NN * 4);
  int* col             = (int*)alloc((size_t)NE * 4);
  int* stmp            = (int*)alloc((size_t)NN * 4);
  int* bsum            = (int*)alloc((size_t)256 * 4);
  unsigned short* h1 = xb;  // reuse: xb dead after GEMM0 consumes it

  // init
  hipMemsetAsync(deg, 0, (size_t)NN * 4, stream);
  hipMemsetAsync(pooled, 0, (size_t)GG * HD * 4, stream);

  // fused prologue: wt transpose x2 + cvtpad + hist
  prep_kernel<<<2816, 256, 0, stream>>>(x, xb, Wr0, Ws0, Wt0, Wr1, Ws1, Wt1, ei, deg);

  // CSR scan + fill
  scan1_kernel<<<SCAN_BLKS, 256, 0, stream>>>(deg, stmp, bsum);
  scan2_kernel<<<1, 256, 0, stream>>>(bsum, row_ptr);
  scan3_kernel<<<SCAN_BLKS, 256, 0, stream>>>(stmp, bsum, row_ptr, cursor);
  fill_kernel<<<(NE + 255) / 256, 256, 0, stream>>>(ei, cursor, col);

  // layer 0
  gather_kernel<<<(MP / 2) / 4, 256, 0, stream>>>(xb, row_ptr, col, aggb);
  gemm_kernel<<<782, 512, 0, stream>>>(aggb, xb, Wt0, br0, h0);

  // layer 1
  gather_kernel<<<(MP / 2) / 4, 256, 0, stream>>>(h0, row_ptr, col, aggb);
  gemm_kernel<<<782, 512, 0, stream>>>(aggb, h0, Wt1, br1, h1);

  // pool + classify
  pool_kernel<<<GG * 16, 256, 0, stream>>>(h1, batch, pooled);
  final_kernel<<<GG, 256, 0, stream>>>(pooled, batch, Wl, bl, out);
}

// Round 6
// 662.419 us; speedup vs baseline: 1.1422x; 1.1422x over previous
//
#include <hip/hip_runtime.h>

// Problem constants
#define NN 50000      // nodes
#define NE 800000     // edges
#define MP 50048      // padded rows
#define GG 64         // graphs
#define HD 512        // hidden/feature dim
#define K2 1024       // fused K (agg | self)
#define SCAN_BLKS 196 // ceil(50000/256)

typedef __attribute__((ext_vector_type(8))) short bf16x8;
typedef __attribute__((ext_vector_type(4))) float f32x4;

__device__ __forceinline__ unsigned short f2bf(float f) {
  unsigned u = __builtin_bit_cast(unsigned, f);
  u += 0x7fffu + ((u >> 16) & 1u);
  return (unsigned short)(u >> 16);
}
__device__ __forceinline__ float bf2f(unsigned short h) {
  unsigned u = ((unsigned)h) << 16;
  return __builtin_bit_cast(float, u);
}

__device__ __forceinline__ void g2l16(const void* g, void* l) {
  __builtin_amdgcn_global_load_lds(
      (const __attribute__((address_space(1))) unsigned int*)g,
      (__attribute__((address_space(3))) unsigned int*)l, 16, 0, 0);
}

// ---------------- fused prologue: weight transpose x2 + x->bf16 pad + degree histogram
__global__ __launch_bounds__(256) void prep_kernel(
    const float* __restrict__ x, unsigned short* __restrict__ xb,
    const float* __restrict__ Wr0, const float* __restrict__ Ws0, unsigned short* __restrict__ Wt0,
    const float* __restrict__ Wr1, const float* __restrict__ Ws1, unsigned short* __restrict__ Wt1,
    const int* __restrict__ ei, int* __restrict__ deg) {
  int b = blockIdx.x, t = threadIdx.x;
  if (b < 256) {
    // 64x64 transpose tile: W[k][n] (fp32) -> Wt[n][half*512+k] (bf16)
    __shared__ float sh[64][65];
    int layer = b >> 7, tl = b & 127;
    int tn = tl >> 4, tk = tl & 15;
    int half = tk >> 3;
    int kw = (tk & 7) * 64, n0 = tn * 64;
    const float* W = layer ? (half ? Ws1 : Wr1) : (half ? Ws0 : Wr0);
    unsigned short* Wt = layer ? Wt1 : Wt0;
    int nn = t & 63;
    int kb = t >> 6;
#pragma unroll
    for (int i = 0; i < 16; i++) {
      int kk = kb + i * 4;
      sh[kk][nn] = W[(size_t)(kw + kk) * HD + n0 + nn];
    }
    __syncthreads();
    int kk2 = t & 63;
#pragma unroll
    for (int i = 0; i < 16; i++) {
      int nn2 = kb + i * 4;
      Wt[(size_t)(n0 + nn2) * K2 + half * HD + kw + kk2] = f2bf(sh[kk2][nn2]);
    }
  } else if (b < 2304) {
    const long long total4 = (long long)MP * HD / 4;
    for (long long i = (long long)(b - 256) * 256 + t; i < total4; i += 2048LL * 256) {
      int r = (int)((i * 4) >> 9);
      float4 v = make_float4(0.f, 0.f, 0.f, 0.f);
      if (r < NN) v = ((const float4*)x)[i];
      ushort4 o;
      o.x = f2bf(v.x); o.y = f2bf(v.y); o.z = f2bf(v.z); o.w = f2bf(v.w);
      ((ushort4*)xb)[i] = o;
    }
  } else {
    for (int i = (b - 2304) * 256 + t; i < NE; i += 512 * 256) {
      atomicAdd(&deg[ei[NE + i]], 1);
    }
  }
}

// ---------------- CSR scan (3-phase) + fill
__global__ __launch_bounds__(256) void scan1_kernel(const int* __restrict__ deg,
                                                    int* __restrict__ tmp,
                                                    int* __restrict__ bsum) {
  __shared__ int sh[256];
  int t = threadIdx.x;
  int i = blockIdx.x * 256 + t;
  int v = (i < NN) ? deg[i] : 0;
  sh[t] = v;
  __syncthreads();
#pragma unroll
  for (int off = 1; off < 256; off <<= 1) {
    int u = (t >= off) ? sh[t - off] : 0;
    __syncthreads();
    sh[t] += u;
    __syncthreads();
  }
  if (i < NN) tmp[i] = sh[t] - v;
  if (t == 255) bsum[blockIdx.x] = sh[255];
}

__global__ __launch_bounds__(256) void scan2_kernel(int* __restrict__ bsum,
                                                    int* __restrict__ row_ptr) {
  __shared__ int sh[256];
  int t = threadIdx.x;
  int v = (t < SCAN_BLKS) ? bsum[t] : 0;
  sh[t] = v;
  __syncthreads();
#pragma unroll
  for (int off = 1; off < 256; off <<= 1) {
    int u = (t >= off) ? sh[t - off] : 0;
    __syncthreads();
    sh[t] += u;
    __syncthreads();
  }
  if (t < SCAN_BLKS) bsum[t] = sh[t] - v;
  if (t == 255) row_ptr[NN] = sh[255];
}

__global__ __launch_bounds__(256) void scan3_kernel(const int* __restrict__ tmp,
                                                    const int* __restrict__ bsum,
                                                    int* __restrict__ row_ptr,
                                                    int* __restrict__ cursor) {
  int i = blockIdx.x * 256 + threadIdx.x;
  if (i < NN) {
    int r = tmp[i] + bsum[blockIdx.x];
    row_ptr[i] = r;
    cursor[i] = r;
  }
}

__global__ void fill_kernel(const int* __restrict__ ei, int* __restrict__ cursor,
                            int* __restrict__ col) {
  int i = blockIdx.x * 256 + threadIdx.x;
  if (i < NE) {
    int d = ei[NE + i];
    int p = atomicAdd(&cursor[d], 1);
    col[p] = ei[i];
  }
}

// ---------------- gather aggregation: 1 row per wave, 8-deep explicit load pipeline
#define ACC8(v, a)                                        \
  a[0] += bf2f((unsigned short)((v).x & 0xffff));         \
  a[1] += bf2f((unsigned short)((v).x >> 16));            \
  a[2] += bf2f((unsigned short)((v).y & 0xffff));         \
  a[3] += bf2f((unsigned short)((v).y >> 16));            \
  a[4] += bf2f((unsigned short)((v).z & 0xffff));         \
  a[5] += bf2f((unsigned short)((v).z >> 16));            \
  a[6] += bf2f((unsigned short)((v).w & 0xffff));         \
  a[7] += bf2f((unsigned short)((v).w >> 16));

__global__ __launch_bounds__(256) void gather_kernel(const unsigned short* __restrict__ X,
                                                     const int* __restrict__ row_ptr,
                                                     const int* __restrict__ col,
                                                     unsigned short* __restrict__ out) {
  int w = (blockIdx.x * 256 + threadIdx.x) >> 6;  // wave id = output row
  int lane = threadIdx.x & 63;
  if (w >= MP) return;
  float a[8] = {0.f, 0.f, 0.f, 0.f, 0.f, 0.f, 0.f, 0.f};
  if (w < NN) {
    int r0 = row_ptr[w], r1 = row_ptr[w + 1];
    const unsigned short* Xl = X + lane * 8;
    for (int base = r0; base < r1; base += 64) {
      int idx = base + lane;
      int myc = (idx < r1) ? col[idx] : 0;
      int cnt = min(64, r1 - base);
      int j = 0;
      // 8-deep batch: issue 8 independent row-loads before any accumulation
      for (; j + 8 <= cnt; j += 8) {
        int c0 = __shfl(myc, j + 0), c1 = __shfl(myc, j + 1);
        int c2 = __shfl(myc, j + 2), c3 = __shfl(myc, j + 3);
        int c4 = __shfl(myc, j + 4), c5 = __shfl(myc, j + 5);
        int c6 = __shfl(myc, j + 6), c7 = __shfl(myc, j + 7);
        uint4 v0 = *(const uint4*)(Xl + (size_t)c0 * HD);
        uint4 v1 = *(const uint4*)(Xl + (size_t)c1 * HD);
        uint4 v2 = *(const uint4*)(Xl + (size_t)c2 * HD);
        uint4 v3 = *(const uint4*)(Xl + (size_t)c3 * HD);
        uint4 v4 = *(const uint4*)(Xl + (size_t)c4 * HD);
        uint4 v5 = *(const uint4*)(Xl + (size_t)c5 * HD);
        uint4 v6 = *(const uint4*)(Xl + (size_t)c6 * HD);
        uint4 v7 = *(const uint4*)(Xl + (size_t)c7 * HD);
        ACC8(v0, a) ACC8(v1, a) ACC8(v2, a) ACC8(v3, a)
        ACC8(v4, a) ACC8(v5, a) ACC8(v6, a) ACC8(v7, a)
      }
      for (; j < cnt; j++) {
        int c = __shfl(myc, j);
        uint4 v = *(const uint4*)(Xl + (size_t)c * HD);
        ACC8(v, a)
      }
    }
  }
  uint4 o;
  o.x = ((unsigned)f2bf(a[1]) << 16) | f2bf(a[0]);
  o.y = ((unsigned)f2bf(a[3]) << 16) | f2bf(a[2]);
  o.z = ((unsigned)f2bf(a[5]) << 16) | f2bf(a[4]);
  o.w = ((unsigned)f2bf(a[7]) << 16) | f2bf(a[6]);
  *(uint4*)(out + (size_t)w * HD + lane * 8) = o;
}

// ---------------- fused GEMM (R4 v2): BM=128, BN=256, BK=64, 512 threads, 2 blocks/CU
__global__ __launch_bounds__(512, 2) void gemm_kernel(
    const unsigned short* __restrict__ A0, const unsigned short* __restrict__ A1,
    const unsigned short* __restrict__ Wt, const float* __restrict__ bias,
    unsigned short* __restrict__ Hout) {
  __shared__ __align__(16) unsigned short Ads[128 * 64];
  __shared__ __align__(16) unsigned short Bds[256 * 64];

  const int tid = threadIdx.x;
  const int lane = tid & 63;
  const int wv = tid >> 6;   // 0..7
  const int wm = wv >> 2;    // 0..1  (64-row slice)
  const int wn = wv & 3;     // 0..3  (64-col slice)

  // bijective XCD-chunk swizzle (m204)
  const int nwg = 782;                 // 391 mt * 2 nt
  const int orig = blockIdx.x;
  const int q = nwg >> 3, r8 = nwg & 7;
  const int xcd = orig & 7;
  const int wgid = (xcd < r8 ? xcd * (q + 1) : r8 * (q + 1) + (xcd - r8) * q) + (orig >> 3);

  const int mt = wgid >> 1;        // 0..390
  const int nt = wgid & 1;         // 0..1
  const int row0 = mt * 128;
  const int col0 = nt * 256;

  f32x4 acc[4][4];
#pragma unroll
  for (int i = 0; i < 4; i++)
#pragma unroll
    for (int j = 0; j < 4; j++) acc[i][j] = (f32x4)(0.f);

  const int lr = lane >> 3;        // row within 8-row staging group
  const int lc = lane & 7;         // 16B chunk within 64-k row
  const int csw = lc ^ lr;         // pre-swizzled source chunk (T2 / m201 pattern)

  for (int kt = 0; kt < 16; ++kt) {
    const int k0 = kt * 64;
    const unsigned short* Asrc = (k0 < HD) ? A0 : A1;
    const int ka = k0 & (HD - 1);
#pragma unroll
    for (int it = 0; it < 2; ++it) {
      int rg = it * 8 + wv;   // 0..15
      g2l16(Asrc + (size_t)(row0 + rg * 8 + lr) * HD + ka + csw * 8, &Ads[rg * 8 * 64]);
    }
#pragma unroll
    for (int it = 0; it < 4; ++it) {
      int rg = it * 8 + wv;   // 0..31
      g2l16(Wt + (size_t)(col0 + rg * 8 + lr) * K2 + k0 + csw * 8, &Bds[rg * 8 * 64]);
    }
    __syncthreads();
#pragma unroll
    for (int kk = 0; kk < 2; ++kk) {
      bf16x8 af[4], bfr[4];
#pragma unroll
      for (int m = 0; m < 4; m++) {
        int r = wm * 64 + m * 16 + (lane & 15);
        int ck = (kk * 4 + (lane >> 4)) ^ (r & 7);
        af[m] = *(const bf16x8*)&Ads[r * 64 + ck * 8];
      }
#pragma unroll
      for (int n = 0; n < 4; n++) {
        int r = wn * 64 + n * 16 + (lane & 15);
        int ck = (kk * 4 + (lane >> 4)) ^ (r & 7);
        bfr[n] = *(const bf16x8*)&Bds[r * 64 + ck * 8];
      }
#pragma unroll
      for (int m = 0; m < 4; m++)
#pragma unroll
        for (int n = 0; n < 4; n++)
          acc[m][n] = __builtin_amdgcn_mfma_f32_16x16x32_bf16(af[m], bfr[n], acc[m][n], 0, 0, 0);
    }
    __syncthreads();
  }

#pragma unroll
  for (int n = 0; n < 4; n++) {
    int c = col0 + wn * 64 + n * 16 + (lane & 15);
    float bv = bias[c];
#pragma unroll
    for (int m = 0; m < 4; m++) {
      int rbase = row0 + wm * 64 + m * 16 + (lane >> 4) * 4;
#pragma unroll
      for (int r = 0; r < 4; r++) {
        float v = acc[m][n][r] + bv;
        v = v > 0.f ? v : 0.f;
        Hout[(size_t)(rbase + r) * HD + c] = f2bf(v);
      }
    }
  }
}

// ---------------- mean-pool partial sums (batch is sorted; binary search boundaries)
__device__ __forceinline__ int lbound(const int* b, int v) {
  int lo = 0, hi = NN;
  while (lo < hi) { int m = (lo + hi) >> 1; if (b[m] < v) lo = m + 1; else hi = m; }
  return lo;
}

__global__ void pool_kernel(const unsigned short* __restrict__ H, const int* __restrict__ batch,
                            float* __restrict__ pooled) {
  int b = blockIdx.x;          // 64 graphs * 2 col-halves * 8 row-chunks
  int g = b >> 4;
  int half = (b >> 3) & 1;
  int chunk = b & 7;
  int col = half * 256 + threadIdx.x;
  int start = lbound(batch, g);
  int end = lbound(batch, g + 1);
  int len = end - start;
  int r0 = start + (int)(((long long)len * chunk) >> 3);
  int r1 = start + (int)(((long long)len * (chunk + 1)) >> 3);
  float s = 0.f;
  for (int r = r0; r < r1; r++) s += bf2f(H[(size_t)r * HD + col]);
  atomicAdd(&pooled[g * HD + col], s);
}

// ---------------- classifier: out[g][c] = relu(pooled/cnt) @ Wl + bl
__global__ void final_kernel(const float* __restrict__ pooled, const int* __restrict__ batch,
                             const float* __restrict__ Wl, const float* __restrict__ bl,
                             float* __restrict__ out) {
  int g = blockIdx.x;
  int t = threadIdx.x;   // 256
  int lane = t & 63, wv = t >> 6;
  int start = lbound(batch, g);
  int end = lbound(batch, g + 1);
  float cnt = (float)(end - start);
  if (cnt < 1.f) cnt = 1.f;
  float a[10];
#pragma unroll
  for (int c = 0; c < 10; c++) a[c] = 0.f;
  for (int n = t; n < HD; n += 256) {
    float p = pooled[g * HD + n] / cnt;
    p = p > 0.f ? p : 0.f;
#pragma unroll
    for (int c = 0; c < 10; c++) a[c] += p * Wl[n * 10 + c];
  }
  __shared__ float red[10][4];
#pragma unroll
  for (int c = 0; c < 10; c++) {
    float v = a[c];
#pragma unroll
    for (int off = 32; off >= 1; off >>= 1) v += __shfl_down(v, off);
    if (lane == 0) red[c][wv] = v;
  }
  __syncthreads();
  if (t < 10) out[g * 10 + t] = red[t][0] + red[t][1] + red[t][2] + red[t][3] + bl[t];
}

extern "C" void kernel_launch(void* const* d_in, const int* in_sizes, int n_in,
                              void* d_out, int out_size, void* d_ws, size_t ws_size,
                              hipStream_t stream) {
  const float* x   = (const float*)d_in[0];
  const int* ei    = (const int*)d_in[1];
  const int* batch = (const int*)d_in[2];
  const float* Wr0 = (const float*)d_in[3];
  const float* br0 = (const float*)d_in[4];
  const float* Ws0 = (const float*)d_in[5];
  const float* Wr1 = (const float*)d_in[6];
  const float* br1 = (const float*)d_in[7];
  const float* Ws1 = (const float*)d_in[8];
  const float* Wl  = (const float*)d_in[9];
  const float* bl  = (const float*)d_in[10];
  float* out = (float*)d_out;

  char* ws = (char*)d_ws;
  size_t off = 0;
  auto alloc = [&](size_t bytes) { char* p = ws + off; off += (bytes + 255) & ~255ULL; return p; };
  unsigned short* xb   = (unsigned short*)alloc((size_t)MP * HD * 2);
  unsigned short* h0   = (unsigned short*)alloc((size_t)MP * HD * 2);
  unsigned short* aggb = (unsigned short*)alloc((size_t)MP * HD * 2);
  unsigned short* Wt0  = (unsigned short*)alloc((size_t)HD * K2 * 2);
  unsigned short* Wt1  = (unsigned short*)alloc((size_t)HD * K2 * 2);
  float* pooled        = (float*)alloc((size_t)GG * HD * 4);
  int* deg             = (int*)alloc((size_t)NN * 4);
  int* row_ptr         = (int*)alloc((size_t)(NN + 1) * 4);
  int* cursor          = (int*)alloc((size_t)NN * 4);
  int* col             = (int*)alloc((size_t)NE * 4);
  int* stmp            = (int*)alloc((size_t)NN * 4);
  int* bsum            = (int*)alloc((size_t)256 * 4);
  unsigned short* h1 = xb;  // reuse: xb dead after GEMM0 consumes it

  // init
  hipMemsetAsync(deg, 0, (size_t)NN * 4, stream);
  hipMemsetAsync(pooled, 0, (size_t)GG * HD * 4, stream);

  // fused prologue: wt transpose x2 + cvtpad + hist
  prep_kernel<<<2816, 256, 0, stream>>>(x, xb, Wr0, Ws0, Wt0, Wr1, Ws1, Wt1, ei, deg);

  // CSR scan + fill
  scan1_kernel<<<SCAN_BLKS, 256, 0, stream>>>(deg, stmp, bsum);
  scan2_kernel<<<1, 256, 0, stream>>>(bsum, row_ptr);
  scan3_kernel<<<SCAN_BLKS, 256, 0, stream>>>(stmp, bsum, row_ptr, cursor);
  fill_kernel<<<(NE + 255) / 256, 256, 0, stream>>>(ei, cursor, col);

  // layer 0
  gather_kernel<<<MP / 4, 256, 0, stream>>>(xb, row_ptr, col, aggb);
  gemm_kernel<<<782, 512, 0, stream>>>(aggb, xb, Wt0, br0, h0);

  // layer 1
  gather_kernel<<<MP / 4, 256, 0, stream>>>(h0, row_ptr, col, aggb);
  gemm_kernel<<<782, 512, 0, stream>>>(aggb, h0, Wt1, br1, h1);

  // pool + classify
  pool_kernel<<<GG * 16, 256, 0, stream>>>(h1, batch, pooled);
  final_kernel<<<GG, 256, 0, stream>>>(pooled, batch, Wl, bl, out);
}